// Round 2
// baseline (513.660 us; speedup 1.0000x reference)
//
#include <hip/hip_runtime.h>

// Problem constants (fixed by setup_inputs).
constexpr int B_    = 4;
constexpr int N_    = 16384;
constexpr int M_    = 1024;
constexpr int C_    = 64;     // feature channels
constexpr int CIN_  = 68;     // 3 rel-pos + 64 features + 1 zero pad (for float4)
constexpr int COP_  = 64;     // neighbor-op out channels
constexpr int COUT_ = 128;    // final out channels
constexpr int K_    = 32;     // neighbors
constexpr float R2_ = 0.25f;  // radius^2
constexpr int CPB_  = 4;      // centers per block (one wave per center)

// One wave per center, 4 centers per 256-thread block.
// Phase 1: ballot-ordered ball-query scan (reads ~128-256 of 16384 cols).
// Phase 2: cooperative gather -> LDS tile X[32][68] with all loads independent
//          and in flight together (no per-iteration dependent latency chain).
// Phase 3: lane j = W_op column j in registers; dot via broadcast float4 LDS
//          reads (conflict-free). Masked max-pool matches the reference's
//          zero-row index_put trick exactly.
// Phase 4: 64->128 aggregation + ReLU.
__global__ __launch_bounds__(256, 4) void pointnet_fused(
    const float* __restrict__ positions,   // (B,N,3)
    const float* __restrict__ features,    // (B,N,64)
    const float* __restrict__ centers,     // (B,M,3)
    const float* __restrict__ distances,   // (B,M,N)
    const float* __restrict__ W_op,        // (67,64)
    const float* __restrict__ b_op,        // (64)
    const float* __restrict__ W_agg,       // (64,128)
    const float* __restrict__ b_agg,       // (128)
    float* __restrict__ out)               // (B,M,128)
{
    const int lane = threadIdx.x & 63;
    const int wv   = threadIdx.x >> 6;               // center slot 0..3
    const int bm   = blockIdx.x * CPB_ + wv;         // global center id
    const int b    = bm >> 10;                       // bm / M_

    __shared__ __align__(16) float s_X[CPB_][K_][CIN_];   // gathered inputs
    __shared__ int   s_ids[CPB_][K_];
    __shared__ float s_pooled[CPB_][COP_];

    // ---- Phase 1: ball query (first K in-range column indices, in order) ----
    const float* drow = distances + (size_t)bm * N_;
    if (lane < K_) s_ids[wv][lane] = 0;              // safe default ids
    int found = 0;
    for (int n0 = 0; n0 < N_ && found < K_; n0 += 64) {
        const float d = drow[n0 + lane];
        const bool pred = d < R2_;
        const unsigned long long m = __ballot(pred);
        const int rank = found + __popcll(m & ((1ull << lane) - 1ull));
        if (pred && rank < K_) s_ids[wv][rank] = n0 + lane;
        found += (int)__popcll(m);
    }
    const int valid = found < K_ ? found : K_;       // wave-uniform
    __syncthreads();

    // ---- Phase 2: cooperative gather into LDS tile ----
    const float ctr0 = centers[bm * 3 + 0];
    const float ctr1 = centers[bm * 3 + 1];
    const float ctr2 = centers[bm * 3 + 2];

    const int myid = s_ids[wv][lane & (K_ - 1)];     // lane k holds id_k (k<32)

    if (lane < K_) {                                 // rel-pos, 32 lanes parallel
        const float* pp = positions + ((size_t)b * N_ + myid) * 3;
        s_X[wv][lane][0]  = pp[0] - ctr0;
        s_X[wv][lane][1]  = pp[1] - ctr1;
        s_X[wv][lane][2]  = pp[2] - ctr2;
        s_X[wv][lane][67] = 0.0f;                    // pad slot
    }
    #pragma unroll 8
    for (int k = 0; k < K_; ++k) {                   // 32 independent coalesced loads
        const int idk = __shfl(myid, k);
        const float f = features[((size_t)b * N_ + idk) * C_ + lane];
        s_X[wv][k][3 + lane] = f;
    }
    __syncthreads();

    // ---- Phase 3: neighbor operator + masked max-pool ----
    float w[CIN_];                                   // W_op column `lane`
    #pragma unroll
    for (int c = 0; c < 67; ++c) w[c] = W_op[c * COP_ + lane];
    w[67] = 0.0f;
    const float bop = b_op[lane];

    const float* Xc = &s_X[wv][0][0];
    float pooled = -INFINITY;
    #pragma unroll 4
    for (int k = 0; k < K_; ++k) {
        const float* row = Xc + k * CIN_;
        float acc = bop;
        #pragma unroll
        for (int c = 0; c < CIN_; c += 4) {
            const float4 x = *(const float4*)(row + c);  // broadcast, conflict-free
            acc = fmaf(x.x, w[c + 0], acc);
            acc = fmaf(x.y, w[c + 1], acc);
            acc = fmaf(x.z, w[c + 2], acc);
            acc = fmaf(x.w, w[c + 3], acc);
        }
        acc = (k < valid) ? acc : 0.0f;              // reference zero-row trick
        pooled = fmaxf(pooled, acc);
    }
    s_pooled[wv][lane] = pooled;
    __syncthreads();

    // ---- Phase 4: aggregation 64 -> 128 + ReLU ----
    float a0 = b_agg[lane];
    float a1 = b_agg[lane + 64];
    #pragma unroll
    for (int jj = 0; jj < COP_; ++jj) {
        const float p = s_pooled[wv][jj];            // broadcast read
        a0 = fmaf(p, W_agg[jj * COUT_ + lane],      a0);
        a1 = fmaf(p, W_agg[jj * COUT_ + lane + 64], a1);
    }
    float* orow = out + (size_t)bm * COUT_;
    orow[lane]      = fmaxf(a0, 0.0f);
    orow[lane + 64] = fmaxf(a1, 0.0f);
}

extern "C" void kernel_launch(void* const* d_in, const int* in_sizes, int n_in,
                              void* d_out, int out_size, void* d_ws, size_t ws_size,
                              hipStream_t stream) {
    const float* positions = (const float*)d_in[0];
    const float* features  = (const float*)d_in[1];
    const float* centers   = (const float*)d_in[2];
    const float* distances = (const float*)d_in[3];
    const float* W_op      = (const float*)d_in[4];
    const float* b_op      = (const float*)d_in[5];
    const float* W_agg     = (const float*)d_in[6];
    const float* b_agg     = (const float*)d_in[7];
    float* out = (float*)d_out;

    dim3 grid((B_ * M_) / CPB_);   // 1024 blocks
    dim3 block(64 * CPB_);         // 256 threads = 4 waves
    pointnet_fused<<<grid, block, 0, stream>>>(
        positions, features, centers, distances,
        W_op, b_op, W_agg, b_agg, out);
}

// Round 3
// 352.938 us; speedup vs baseline: 1.4554x; 1.4554x over previous
//
#include <hip/hip_runtime.h>

// Problem constants (fixed by setup_inputs).
constexpr int B_    = 4;
constexpr int N_    = 16384;
constexpr int M_    = 1024;
constexpr int C_    = 64;     // feature channels
constexpr int COP_  = 64;     // neighbor-op out channels
constexpr int COUT_ = 128;    // final out channels
constexpr int K_    = 32;     // neighbors
constexpr float R2_ = 0.25f;  // radius^2

// One wave (64 lanes) per center, 4096 single-wave blocks, no barriers.
// Phase 1: ballot-ordered ball-query scan (early-exits after ~2-3 rounds of 64
//          cols; uniform-random distances put all hits in the first ~200 cols).
// Phase 2: all 32 neighbor ids land in registers (one ds_read of the 128 B id
//          buffer); fully-unrolled neighbor loop uses compile-time
//          v_readlane -> SGPR id -> wave-uniform feature row base -> the
//          compiler emits batched s_load (scalar cache) and pipelines the 32
//          independent neighbor bodies. Lane j owns W_op column j in VGPRs;
//          inner loop is pure v_fma with one SGPR operand.
// Phase 3: masked max-pool exactly matches the reference zero-row trick.
// Phase 4: 64->128 aggregation via readlane broadcast (no LDS), + ReLU.
__global__ __launch_bounds__(64) void pointnet_fused(
    const float* __restrict__ positions,   // (B,N,3)
    const float* __restrict__ features,    // (B,N,64)
    const float* __restrict__ centers,     // (B,M,3)
    const float* __restrict__ distances,   // (B,M,N)
    const float* __restrict__ W_op,        // (67,64)
    const float* __restrict__ b_op,        // (64)
    const float* __restrict__ W_agg,       // (64,128)
    const float* __restrict__ b_agg,       // (128)
    float* __restrict__ out)               // (B,M,128)
{
    const int lane = threadIdx.x;          // 0..63
    const int bm   = blockIdx.x;           // center id
    const int b    = bm >> 10;             // bm / M_
    const int bN   = b * N_;

    __shared__ int s_ids[K_];
    if (lane < K_) s_ids[lane] = 0;        // safe default (masked by `valid`)

    // ---- Phase 1: ball query (first K in-range column indices, in order) ----
    const float* drow = distances + (size_t)bm * N_;
    int found = 0;
    for (int n0 = 0; n0 < N_ && found < K_; n0 += 64) {
        const float d = drow[n0 + lane];
        const bool pred = d < R2_;
        const unsigned long long m = __ballot(pred);
        const int rank = found + __popcll(m & ((1ull << lane) - 1ull));
        if (pred && rank < K_) s_ids[rank] = n0 + lane;
        found += (int)__popcll(m);
    }
    const int valid = found < K_ ? found : K_;   // wave-uniform

    // W_op column `lane` -> registers (coalesced across lanes).
    float w[67];
    #pragma unroll
    for (int c = 0; c < 67; ++c) w[c] = W_op[c * COP_ + lane];
    const float bop  = b_op[lane];
    const float ctr0 = centers[bm * 3 + 0];
    const float ctr1 = centers[bm * 3 + 1];
    const float ctr2 = centers[bm * 3 + 2];

    // Lane k (k<32) holds id_k; single in-wave LDS read, no barrier needed.
    const int myid = s_ids[lane & (K_ - 1)];

    // ---- Phase 2+3: neighbor operator + masked max-pool ----
    float pooled = -INFINITY;
    #pragma unroll
    for (int k = 0; k < K_; ++k) {
        const int id = __builtin_amdgcn_readlane(myid, k);   // SGPR, uniform
        const float*  pp = positions + (size_t)(bN + id) * 3;
        const float4* f4 = (const float4*)(features + (size_t)(bN + id) * C_);
        float acc = bop;
        acc = fmaf(pp[0] - ctr0, w[0], acc);
        acc = fmaf(pp[1] - ctr1, w[1], acc);
        acc = fmaf(pp[2] - ctr2, w[2], acc);
        #pragma unroll
        for (int c4 = 0; c4 < 16; ++c4) {
            const float4 x = f4[c4];                         // uniform s_load
            acc = fmaf(x.x, w[3 + 4 * c4 + 0], acc);
            acc = fmaf(x.y, w[3 + 4 * c4 + 1], acc);
            acc = fmaf(x.z, w[3 + 4 * c4 + 2], acc);
            acc = fmaf(x.w, w[3 + 4 * c4 + 3], acc);
        }
        pooled = (k < valid) ? fmaxf(pooled, acc) : pooled;
    }
    // Invalid slots contribute f = 0 (reference index_put zero-row trick).
    if (valid < K_) pooled = fmaxf(pooled, 0.0f);

    // ---- Phase 4: aggregation 64 -> 128 + ReLU (readlane broadcast) ----
    float a0 = b_agg[lane];
    float a1 = b_agg[lane + 64];
    #pragma unroll
    for (int jj = 0; jj < COP_; ++jj) {
        const float p = __int_as_float(
            __builtin_amdgcn_readlane(__float_as_int(pooled), jj));
        a0 = fmaf(p, W_agg[jj * COUT_ + lane],      a0);
        a1 = fmaf(p, W_agg[jj * COUT_ + lane + 64], a1);
    }
    float* orow = out + (size_t)bm * COUT_;
    orow[lane]      = fmaxf(a0, 0.0f);
    orow[lane + 64] = fmaxf(a1, 0.0f);
}

extern "C" void kernel_launch(void* const* d_in, const int* in_sizes, int n_in,
                              void* d_out, int out_size, void* d_ws, size_t ws_size,
                              hipStream_t stream) {
    const float* positions = (const float*)d_in[0];
    const float* features  = (const float*)d_in[1];
    const float* centers   = (const float*)d_in[2];
    const float* distances = (const float*)d_in[3];
    const float* W_op      = (const float*)d_in[4];
    const float* b_op      = (const float*)d_in[5];
    const float* W_agg     = (const float*)d_in[6];
    const float* b_agg     = (const float*)d_in[7];
    float* out = (float*)d_out;

    dim3 grid(B_ * M_);   // 4096 single-wave blocks
    dim3 block(64);
    pointnet_fused<<<grid, block, 0, stream>>>(
        positions, features, centers, distances,
        W_op, b_op, W_agg, b_agg, out);
}

// Round 4
// 326.570 us; speedup vs baseline: 1.5729x; 1.0807x over previous
//
#include <hip/hip_runtime.h>

// Problem constants (fixed by setup_inputs).
constexpr int B_    = 4;
constexpr int N_    = 16384;
constexpr int M_    = 1024;
constexpr int C_    = 64;     // feature channels
constexpr int COP_  = 64;     // neighbor-op out channels
constexpr int COUT_ = 128;    // final out channels
constexpr int K_    = 32;     // neighbors
constexpr float R2_ = 0.25f;  // radius^2

typedef __attribute__((ext_vector_type(8)))  short bf16x8;   // MFMA A/B frag (4 VGPR)
typedef __attribute__((ext_vector_type(16))) float f32x16;   // MFMA C/D frag

// fp32 -> bf16 round-to-nearest-even (data is finite; NaN path not needed).
static __device__ __forceinline__ short f2bf(float f) {
    union { float f; unsigned u; } v; v.f = f;
    const unsigned r = v.u + 0x7fffu + ((v.u >> 16) & 1u);
    return (short)(r >> 16);
}

// One wave per center, 4096 single-wave blocks, no barriers.
// K-dim ordering for the neighbor-op GEMM: k=0..63 -> feature channel k,
// k=64..66 -> rel-pos dim k-64, k=67..79 -> zero pad (K=80 = 5 MFMA steps).
// A (32 neighbors x 80) is loaded from global DIRECTLY in MFMA A-fragment
// layout (lane l: rows m=l&31, k=(l>>5)*8+j => two aligned float4 per step).
// W_op held in registers as B-fragments; 10 chained v_mfma_f32_32x32x16_bf16
// replace ~2272 scalar FMAs. C/D layout (verified m74/m101):
//   col = lane&31, row = (reg&3) + 8*(reg>>2) + 4*(lane>>5).
__global__ __launch_bounds__(64) void pointnet_fused(
    const float* __restrict__ positions,   // (B,N,3)
    const float* __restrict__ features,    // (B,N,64)
    const float* __restrict__ centers,     // (B,M,3)
    const float* __restrict__ distances,   // (B,M,N)
    const float* __restrict__ W_op,        // (67,64)
    const float* __restrict__ b_op,        // (64)
    const float* __restrict__ W_agg,       // (64,128)
    const float* __restrict__ b_agg,       // (128)
    float* __restrict__ out)               // (B,M,128)
{
    const int lane = threadIdx.x;          // 0..63
    const int bm   = blockIdx.x;           // center id
    const int b    = bm >> 10;             // bm / M_
    const int bN   = b * N_;

    __shared__ int s_ids[K_];
    if (lane < K_) s_ids[lane] = 0;        // safe default (masked by `valid`)

    // ---- Phase 1: ball query. First 4 chunks (256 cols) load as 4
    // independent dwords -> one memory latency instead of 2-4 serial rounds.
    const float* drow = distances + (size_t)bm * N_;
    float dch[4];
    #pragma unroll
    for (int i = 0; i < 4; ++i) dch[i] = drow[64 * i + lane];
    const unsigned long long ltmask = (1ull << lane) - 1ull;
    int found = 0;
    #pragma unroll
    for (int i = 0; i < 4; ++i) {
        const bool pred = dch[i] < R2_;
        const unsigned long long mi = __ballot(pred);
        const int rank = found + __popcll(mi & ltmask);
        if (pred && rank < K_) s_ids[rank] = 64 * i + lane;
        found += (int)__popcll(mi);
    }
    for (int n0 = 256; n0 < N_ && found < K_; n0 += 64) {   // ~never taken
        const float d = drow[n0 + lane];
        const bool pred = d < R2_;
        const unsigned long long mi = __ballot(pred);
        const int rank = found + __popcll(mi & ltmask);
        if (pred && rank < K_) s_ids[rank] = n0 + lane;
        found += (int)__popcll(mi);
    }
    const int valid = found < K_ ? found : K_;   // wave-uniform

    const float ctr0 = centers[bm * 3 + 0];
    const float ctr1 = centers[bm * 3 + 1];
    const float ctr2 = centers[bm * 3 + 2];

    // Lane l serves A-matrix row m = l&31 (both half-waves read the same id).
    const int rowid = s_ids[lane & (K_ - 1)];
    const int koff  = (lane >> 5) * 8;           // 0 or 8: k-subrange of this half

    // ---- Phase 2a: A fragments straight from global (independent loads) ----
    const float* frow = features + (size_t)(bN + rowid) * C_;
    float4 xa[8];
    #pragma unroll
    for (int s = 0; s < 4; ++s) {
        xa[2 * s]     = *(const float4*)(frow + 16 * s + koff);
        xa[2 * s + 1] = *(const float4*)(frow + 16 * s + koff + 4);
    }
    const float* prow = positions + (size_t)(bN + rowid) * 3;
    const float r0 = prow[0] - ctr0;             // used by lanes with koff==0
    const float r1 = prow[1] - ctr1;
    const float r2 = prow[2] - ctr2;

    bf16x8 afr[5];
    #pragma unroll
    for (int s = 0; s < 4; ++s) {
        afr[s][0] = f2bf(xa[2 * s].x);     afr[s][1] = f2bf(xa[2 * s].y);
        afr[s][2] = f2bf(xa[2 * s].z);     afr[s][3] = f2bf(xa[2 * s].w);
        afr[s][4] = f2bf(xa[2 * s + 1].x); afr[s][5] = f2bf(xa[2 * s + 1].y);
        afr[s][6] = f2bf(xa[2 * s + 1].z); afr[s][7] = f2bf(xa[2 * s + 1].w);
    }
    #pragma unroll
    for (int j = 0; j < 8; ++j) afr[4][j] = 0;   // step 4: rel-pos + pad
    if (koff == 0) { afr[4][0] = f2bf(r0); afr[4][1] = f2bf(r1); afr[4][2] = f2bf(r2); }

    // ---- Phase 2b: W_op as B-fragments (registers, 2 N-tiles x 5 K-steps) ----
    const int n0col = lane & 31;
    bf16x8 bfr[2][5];
    #pragma unroll
    for (int t = 0; t < 2; ++t) {
        const int n = 32 * t + n0col;
        #pragma unroll
        for (int s = 0; s < 4; ++s)                  // k = 16s+koff+j < 64: features
            #pragma unroll
            for (int j = 0; j < 8; ++j)
                bfr[t][s][j] = f2bf(W_op[(3 + 16 * s + koff + j) * COP_ + n]);
        #pragma unroll
        for (int j = 0; j < 8; ++j) {                // k >= 64: rel-pos rows / pad
            const int c = koff + j;
            bfr[t][4][j] = (c < 3) ? f2bf(W_op[c * COP_ + n]) : (short)0;
        }
    }

    // ---- Phase 3: 10 MFMAs ----
    f32x16 acc0, acc1;
    #pragma unroll
    for (int i = 0; i < 16; ++i) { acc0[i] = 0.0f; acc1[i] = 0.0f; }
    #pragma unroll
    for (int s = 0; s < 5; ++s) {
        acc0 = __builtin_amdgcn_mfma_f32_32x32x16_bf16(afr[s], bfr[0][s], acc0, 0, 0, 0);
        acc1 = __builtin_amdgcn_mfma_f32_32x32x16_bf16(afr[s], bfr[1][s], acc1, 0, 0, 0);
    }

    // ---- bias + mask (reference zero-row trick) + max over neighbors ----
    const float bb0 = b_op[n0col];
    const float bb1 = b_op[32 + n0col];
    const int mbase = 4 * (lane >> 5);
    float p0 = -INFINITY, p1 = -INFINITY;
    #pragma unroll
    for (int r = 0; r < 16; ++r) {
        const int m = (r & 3) + 8 * (r >> 2) + mbase;  // neighbor slot of this reg
        const bool ok = m < valid;
        p0 = fmaxf(p0, ok ? (acc0[r] + bb0) : 0.0f);
        p1 = fmaxf(p1, ok ? (acc1[r] + bb1) : 0.0f);
    }
    p0 = fmaxf(p0, __shfl_xor(p0, 32));   // combine the two half-wave row sets
    p1 = fmaxf(p1, __shfl_xor(p1, 32));
    // Now every lane: p0 = pooled[lane&31], p1 = pooled[32+(lane&31)].

    // ---- Phase 4: aggregation 64 -> 128 + ReLU (readlane broadcast) ----
    float a0 = b_agg[lane];
    float a1 = b_agg[lane + 64];
    #pragma unroll
    for (int jj = 0; jj < 32; ++jj) {
        const float q0 = __int_as_float(__builtin_amdgcn_readlane(__float_as_int(p0), jj));
        a0 = fmaf(q0, W_agg[jj * COUT_ + lane],      a0);
        a1 = fmaf(q0, W_agg[jj * COUT_ + lane + 64], a1);
        const float q1 = __int_as_float(__builtin_amdgcn_readlane(__float_as_int(p1), jj));
        a0 = fmaf(q1, W_agg[(32 + jj) * COUT_ + lane],      a0);
        a1 = fmaf(q1, W_agg[(32 + jj) * COUT_ + lane + 64], a1);
    }
    float* orow = out + (size_t)bm * COUT_;
    orow[lane]      = fmaxf(a0, 0.0f);
    orow[lane + 64] = fmaxf(a1, 0.0f);
}

extern "C" void kernel_launch(void* const* d_in, const int* in_sizes, int n_in,
                              void* d_out, int out_size, void* d_ws, size_t ws_size,
                              hipStream_t stream) {
    const float* positions = (const float*)d_in[0];
    const float* features  = (const float*)d_in[1];
    const float* centers   = (const float*)d_in[2];
    const float* distances = (const float*)d_in[3];
    const float* W_op      = (const float*)d_in[4];
    const float* b_op      = (const float*)d_in[5];
    const float* W_agg     = (const float*)d_in[6];
    const float* b_agg     = (const float*)d_in[7];
    float* out = (float*)d_out;

    dim3 grid(B_ * M_);   // 4096 single-wave blocks
    dim3 block(64);
    pointnet_fused<<<grid, block, 0, stream>>>(
        positions, features, centers, distances,
        W_op, b_op, W_agg, b_agg, out);
}